// Round 1
// baseline (400.068 us; speedup 1.0000x reference)
//
#include <hip/hip_runtime.h>

// Batched EKF step: predict(dt, Q) then update(z, R).
// x:[B,6,1] P:[B,6,6] dt:[B] Q:[B,6,6] z:[B,3,1] R:[B,3,3]
// out = concat(x_upd [B,6,1], P_upd [B,6,6]) flat fp32.
//
// R4 (this round):
//   - Latency-bound at 32% HBM (101 us kernel, VALUBusy 9.7%). Fix = MLP:
//     2 tracklets/thread, ALL global loads issued up front (18 float4 + both
//     tiles' x/z/dt). Tile B waits in registers while tile A computes.
//   - BLK=64 == one wave, so __syncthreads is replaced by a pure
//     "s_waitcnt lgkmcnt(0)" fence: per-wave LDS ops execute in order, and
//     dropping the barrier removes the vmcnt(0) drain __syncthreads implies
//     (which would have stalled tile A on tile B's in-flight loads and the
//     A->B transition on A's store acks).
//   - LDS buffer (9472 B) reused serially by both tiles -> occupancy still
//     16 blocks/CU, but bytes-in-flight per wave doubled.
// R3 (kept): uniform Q/R via lane-uniform s_loads; coalesced float4 P
//     stage through LDS; pad 37 -> 2 lanes/bank (free).

#define BLK  64
#define PADP 37   // pad for 36-float rows: bank (5t+j)%32, 2-way = free

#define WAVE_SYNC() asm volatile("s_waitcnt lgkmcnt(0)" ::: "memory")

__device__ __forceinline__ void process_tile(
    float* sm, const int tid,
    const float4 pv[9], const float dt,
    const float x[6], const float zv[3],
    const float Qu[36], const float Ru[9],
    const bool valid, const int lim, const int b0,
    float* __restrict__ x_out, float* __restrict__ P_out)
{
    // ---- transpose P through LDS: lane-contiguous -> per-thread rows ----
#pragma unroll
    for (int k = 0; k < 9; ++k) {
        int m = tid + k*BLK;
        int r = m / 9, c = m - r*9;
        float* d = &sm[r*PADP + c*4];
        d[0]=pv[k].x; d[1]=pv[k].y; d[2]=pv[k].z; d[3]=pv[k].w;
    }
    WAVE_SYNC();

    float P[36];
#pragma unroll
    for (int j = 0; j < 36; ++j) P[j] = sm[tid*PADP + j];

    // ---- predict ----
    float xp[6];
#pragma unroll
    for (int i = 0; i < 3; ++i) xp[i] = fmaf(dt, x[i+3], x[i]);
    xp[3]=x[3]; xp[4]=x[4]; xp[5]=x[5];

    // FP = F @ P : row i (<3) += dt * row (i+3)
    float FP[36];
#pragma unroll
    for (int i = 0; i < 6; ++i) {
#pragma unroll
        for (int j = 0; j < 6; ++j) {
            float v = P[i*6 + j];
            if (i < 3) v = fmaf(dt, P[(i+3)*6 + j], v);
            FP[i*6 + j] = v;
        }
    }

    // P_pred = FP @ F^T + Q : col j (<3) += dt * col (j+3)
    float Pp[36];
#pragma unroll
    for (int i = 0; i < 6; ++i) {
#pragma unroll
        for (int j = 0; j < 6; ++j) {
            float v = FP[i*6 + j];
            if (j < 3) v = fmaf(dt, FP[i*6 + j + 3], v);
            Pp[i*6 + j] = v + Qu[i*6 + j];
        }
    }

    // ---- update ----
    const float S00 = Pp[0]  + Ru[0], S01 = Pp[1]  + Ru[1], S02 = Pp[2]  + Ru[2];
    const float S10 = Pp[6]  + Ru[3], S11 = Pp[7]  + Ru[4], S12 = Pp[8]  + Ru[5];
    const float S20 = Pp[12] + Ru[6], S21 = Pp[13] + Ru[7], S22 = Pp[14] + Ru[8];

    const float c00 =  (S11*S22 - S12*S21);
    const float c01 = -(S10*S22 - S12*S20);
    const float c02 =  (S10*S21 - S11*S20);
    const float c10 = -(S01*S22 - S02*S21);
    const float c11 =  (S00*S22 - S02*S20);
    const float c12 = -(S00*S21 - S01*S20);
    const float c20 =  (S01*S12 - S02*S11);
    const float c21 = -(S00*S12 - S02*S10);
    const float c22 =  (S00*S11 - S01*S10);
    const float det  = S00*c00 + S01*c01 + S02*c02;
    const float rdet = 1.0f / det;

    float Si[9];
    Si[0]=c00*rdet; Si[1]=c10*rdet; Si[2]=c20*rdet;
    Si[3]=c01*rdet; Si[4]=c11*rdet; Si[5]=c21*rdet;
    Si[6]=c02*rdet; Si[7]=c12*rdet; Si[8]=c22*rdet;

    float K[18];
#pragma unroll
    for (int i = 0; i < 6; ++i) {
#pragma unroll
        for (int a = 0; a < 3; ++a) {
            K[i*3+a] = Pp[i*6+0]*Si[0*3+a] + Pp[i*6+1]*Si[1*3+a] + Pp[i*6+2]*Si[2*3+a];
        }
    }

    const float iv0 = zv[0] - xp[0];
    const float iv1 = zv[1] - xp[1];
    const float iv2 = zv[2] - xp[2];

    float xu[6];
#pragma unroll
    for (int i = 0; i < 6; ++i)
        xu[i] = xp[i] + K[i*3+0]*iv0 + K[i*3+1]*iv1 + K[i*3+2]*iv2;

    if (valid) {
        float2* p = (float2*)(x_out + (size_t)(b0 + tid) * 6);
        p[0] = make_float2(xu[0], xu[1]);
        p[1] = make_float2(xu[2], xu[3]);
        p[2] = make_float2(xu[4], xu[5]);
    }

    WAVE_SYNC();  // P-tile reads returned (intra-wave; LDS pipe is in-order)

    // P_upd = Pp - K @ Pp[:3,:] -> padded LDS rows
#pragma unroll
    for (int i = 0; i < 6; ++i) {
#pragma unroll
        for (int j = 0; j < 6; ++j) {
            sm[tid*PADP + i*6 + j] =
                Pp[i*6 + j] - (K[i*3+0]*Pp[j] + K[i*3+1]*Pp[6+j] + K[i*3+2]*Pp[12+j]);
        }
    }
    WAVE_SYNC();

    // ---- coalesced float4 store of P_upd ----
    {
        float4* gq = (float4*)P_out + (size_t)b0 * 9;
#pragma unroll
        for (int k = 0; k < 9; ++k) {
            int m = tid + k*BLK;
            if (m < lim) {
                int r = m / 9, c = m - r*9;
                const float* s = &sm[r*PADP + c*4];
                gq[m] = make_float4(s[0], s[1], s[2], s[3]);
            }
        }
    }
}

__global__ __launch_bounds__(BLK, 4)
void ekf_step_kernel(const float* __restrict__ x_in,
                     const float* __restrict__ P_in,
                     const float* __restrict__ dt_in,
                     const float* __restrict__ Q_in,
                     const float* __restrict__ z_in,
                     const float* __restrict__ R_in,
                     float* __restrict__ x_out,
                     float* __restrict__ P_out,
                     int B)
{
    __shared__ float sm[BLK * PADP];  // 9472 B, reused serially by both tiles

    const int tid = threadIdx.x;
    const int b0  = blockIdx.x * (BLK * 2);
    const int bA  = b0;
    const int bB  = b0 + BLK;

    const int limA = min(BLK, B - bA) * 9;   // <=0 handled by guards
    const int limB = min(BLK, B - bB) * 9;

    // ---- uniform Q (6x6) and R (3x3): broadcast inputs, row 0 only ----
    float Qu[36];
#pragma unroll
    for (int j = 0; j < 36; ++j) Qu[j] = Q_in[j];   // uniform -> s_load
    float Ru[9];
#pragma unroll
    for (int j = 0; j < 9; ++j) Ru[j] = R_in[j];    // uniform -> s_load

    // ---- issue ALL global loads up front: both P tiles, then smalls ----
    const float4* gp = (const float4*)P_in;
    float4 pvA[9], pvB[9];
#pragma unroll
    for (int k = 0; k < 9; ++k) {
        int m = tid + k*BLK;
        pvA[k] = make_float4(0.f, 0.f, 0.f, 0.f);
        if (m < limA) pvA[k] = gp[(size_t)bA * 9 + m];
    }
#pragma unroll
    for (int k = 0; k < 9; ++k) {
        int m = tid + k*BLK;
        pvB[k] = make_float4(0.f, 0.f, 0.f, 0.f);
        if (m < limB) pvB[k] = gp[(size_t)bB * 9 + m];
    }

    const int tA = bA + tid, tB = bB + tid;
    const bool vA = (tA < B), vB = (tB < B);

    const float dtA = vA ? dt_in[tA] : 0.0f;
    const float dtB = vB ? dt_in[tB] : 0.0f;

    float xA[6] = {0,0,0,0,0,0}, xB[6] = {0,0,0,0,0,0};
    if (vA) {
        const float2* p = (const float2*)(x_in + (size_t)tA * 6);
        float2 a = p[0], b = p[1], c = p[2];
        xA[0]=a.x; xA[1]=a.y; xA[2]=b.x; xA[3]=b.y; xA[4]=c.x; xA[5]=c.y;
    }
    if (vB) {
        const float2* p = (const float2*)(x_in + (size_t)tB * 6);
        float2 a = p[0], b = p[1], c = p[2];
        xB[0]=a.x; xB[1]=a.y; xB[2]=b.x; xB[3]=b.y; xB[4]=c.x; xB[5]=c.y;
    }

    float zA[3] = {0,0,0}, zB[3] = {0,0,0};
    if (vA) {
        const float* p = z_in + (size_t)tA * 3;
        zA[0]=p[0]; zA[1]=p[1]; zA[2]=p[2];
    }
    if (vB) {
        const float* p = z_in + (size_t)tB * 3;
        zB[0]=p[0]; zB[1]=p[1]; zB[2]=p[2];
    }

    // ---- tile A: compute while tile B's loads are still in flight ----
    process_tile(sm, tid, pvA, dtA, xA, zA, Qu, Ru, vA, limA, bA, x_out, P_out);
    WAVE_SYNC();  // A's gather reads done before B's stage overwrites sm
    process_tile(sm, tid, pvB, dtB, xB, zB, Qu, Ru, vB, limB, bB, x_out, P_out);
}

extern "C" void kernel_launch(void* const* d_in, const int* in_sizes, int n_in,
                              void* d_out, int out_size, void* d_ws, size_t ws_size,
                              hipStream_t stream) {
    const float* x_in  = (const float*)d_in[0];
    const float* P_in  = (const float*)d_in[1];
    const float* dt_in = (const float*)d_in[2];
    const float* Q_in  = (const float*)d_in[3];
    const float* z_in  = (const float*)d_in[4];
    const float* R_in  = (const float*)d_in[5];

    const int B = in_sizes[2];  // delta_t is [B]

    float* x_out = (float*)d_out;                    // [B,6]
    float* P_out = (float*)d_out + (size_t)B * 6;    // [B,36]

    const int TILE = BLK * 2;
    const int grid = (B + TILE - 1) / TILE;
    ekf_step_kernel<<<grid, BLK, 0, stream>>>(x_in, P_in, dt_in, Q_in, z_in, R_in,
                                              x_out, P_out, B);
}

// Round 4
// 382.933 us; speedup vs baseline: 1.0447x; 1.0447x over previous
//
#include <hip/hip_runtime.h>

// Batched EKF step: predict(dt, Q) then update(z, R).
// x:[B,6,1] P:[B,6,6] dt:[B] Q:[B,6,6] z:[B,3,1] R:[B,3,3]
// out = concat(x_upd [B,6,1], P_upd [B,6,6]) flat fp32.
//
// R7 = R5 design, third submission (R5/R6 benches died with "MI355X
//   container failed twice" -- broker infra fault both times; kernel audited:
//   straight-line, no barriers, all accesses in-bounds, cannot hang).
//   Kernel symbol renamed to defeat any stale-container build cache.
//
// R5 design:
//   - R4 post-mortem: 2-tile register prefetch SPILLED (WRITE_SIZE +96 MB,
//     FETCH +50 MB of scratch traffic, 127 us). Reverted.
//   - LDS transpose removed entirely. Per-thread direct row access
//     (9x float4 @ stride 144 B) touches the same fully-consumed cache
//     lines per wave as the coalesced+LDS-transpose path -> identical HBM
//     traffic, but: no LDS occupancy cap (was 16 waves/CU), no bank
//     conflicts (was 2.25M cy), no lgkm serialization, and the 36 staging
//     VGPRs are freed.
//   - Predict step computed fully IN PLACE in P[36]:
//       F@P   : row i (<3) += dt * row (i+3)   (rows 3-5 untouched)
//       (.)F^T: col j (<3) += dt * col (j+3)   (cols 3-5 untouched)
//     -> no FP[36]/Pp[36] copies; peak live ~80 VGPRs.
//   - BLK=256, __launch_bounds__(256,5): VGPR cap 102 >> est. peak 80,
//     deliberate headroom so the R4 spill mode cannot recur. Target
//     5-6 waves/EU (62-75% occupancy vs 36.8%).
// R3 (kept): uniform Q/R via lane-uniform s_loads; float4/float2 vector
//     loads and stores.

#define BLK 256

__global__ __launch_bounds__(BLK, 5)
void ekf_step_r7(const float* __restrict__ x_in,
                 const float* __restrict__ P_in,
                 const float* __restrict__ dt_in,
                 const float* __restrict__ Q_in,
                 const float* __restrict__ z_in,
                 const float* __restrict__ R_in,
                 float* __restrict__ x_out,
                 float* __restrict__ P_out,
                 int B)
{
    const int t = blockIdx.x * BLK + threadIdx.x;
    if (t >= B) return;   // no barriers anywhere: early-exit is safe

    // ---- uniform Q (6x6) and R (3x3): broadcast inputs, row 0 only ----
    float Qu[36];
#pragma unroll
    for (int j = 0; j < 36; ++j) Qu[j] = Q_in[j];   // uniform -> s_load
    float Ru[9];
#pragma unroll
    for (int j = 0; j < 9; ++j) Ru[j] = R_in[j];    // uniform -> s_load

    // ---- issue the long-pole loads first: own P row, 9x float4 ----
    float P[36];
    {
        const float4* pr = (const float4*)(P_in + (size_t)t * 36);
#pragma unroll
        for (int k = 0; k < 9; ++k) {
            float4 v = pr[k];
            P[k*4+0] = v.x; P[k*4+1] = v.y; P[k*4+2] = v.z; P[k*4+3] = v.w;
        }
    }

    const float dt = dt_in[t];

    float x[6];
    {
        const float2* p = (const float2*)(x_in + (size_t)t * 6);
        float2 a = p[0], b = p[1], c = p[2];
        x[0]=a.x; x[1]=a.y; x[2]=b.x; x[3]=b.y; x[4]=c.x; x[5]=c.y;
    }
    float zv[3];
    {
        const float* p = z_in + (size_t)t * 3;   // 12 B, not float2-aligned
        zv[0]=p[0]; zv[1]=p[1]; zv[2]=p[2];
    }

    // ---- predict: x_pred ----
    float xp[6];
#pragma unroll
    for (int i = 0; i < 3; ++i) xp[i] = fmaf(dt, x[i+3], x[i]);
    xp[3]=x[3]; xp[4]=x[4]; xp[5]=x[5];

    // ---- predict: P = F @ P @ F^T + Q, fully in place ----
#pragma unroll
    for (int i = 0; i < 3; ++i)          // F @ P
#pragma unroll
        for (int j = 0; j < 6; ++j)
            P[i*6+j] = fmaf(dt, P[(i+3)*6+j], P[i*6+j]);
#pragma unroll
    for (int i = 0; i < 6; ++i)          // (.) @ F^T
#pragma unroll
        for (int j = 0; j < 3; ++j)
            P[i*6+j] = fmaf(dt, P[i*6+j+3], P[i*6+j]);
#pragma unroll
    for (int j = 0; j < 36; ++j)         // + Q
        P[j] += Qu[j];

    // ---- update: S = P[:3,:3] + R, invert 3x3 via adjugate ----
    const float S00 = P[0]  + Ru[0], S01 = P[1]  + Ru[1], S02 = P[2]  + Ru[2];
    const float S10 = P[6]  + Ru[3], S11 = P[7]  + Ru[4], S12 = P[8]  + Ru[5];
    const float S20 = P[12] + Ru[6], S21 = P[13] + Ru[7], S22 = P[14] + Ru[8];

    const float c00 =  (S11*S22 - S12*S21);
    const float c01 = -(S10*S22 - S12*S20);
    const float c02 =  (S10*S21 - S11*S20);
    const float c10 = -(S01*S22 - S02*S21);
    const float c11 =  (S00*S22 - S02*S20);
    const float c12 = -(S00*S21 - S01*S20);
    const float c20 =  (S01*S12 - S02*S11);
    const float c21 = -(S00*S12 - S02*S10);
    const float c22 =  (S00*S11 - S01*S10);
    const float det  = S00*c00 + S01*c01 + S02*c02;
    const float rdet = 1.0f / det;

    float Si[9];
    Si[0]=c00*rdet; Si[1]=c10*rdet; Si[2]=c20*rdet;
    Si[3]=c01*rdet; Si[4]=c11*rdet; Si[5]=c21*rdet;
    Si[6]=c02*rdet; Si[7]=c12*rdet; Si[8]=c22*rdet;

    // ---- K = P[:, :3] @ Si ----
    float K[18];
#pragma unroll
    for (int i = 0; i < 6; ++i)
#pragma unroll
        for (int a = 0; a < 3; ++a)
            K[i*3+a] = P[i*6+0]*Si[0*3+a] + P[i*6+1]*Si[1*3+a] + P[i*6+2]*Si[2*3+a];

    // ---- x_upd ----
    const float iv0 = zv[0] - xp[0];
    const float iv1 = zv[1] - xp[1];
    const float iv2 = zv[2] - xp[2];

    float xu[6];
#pragma unroll
    for (int i = 0; i < 6; ++i)
        xu[i] = xp[i] + K[i*3+0]*iv0 + K[i*3+1]*iv1 + K[i*3+2]*iv2;

    {
        float2* p = (float2*)(x_out + (size_t)t * 6);
        p[0] = make_float2(xu[0], xu[1]);
        p[1] = make_float2(xu[2], xu[3]);
        p[2] = make_float2(xu[4], xu[5]);
    }

    // ---- P_upd = P - K @ P[:3,:], in place (save top 3 rows first) ----
    float T[18];
#pragma unroll
    for (int j = 0; j < 18; ++j) T[j] = P[j];
#pragma unroll
    for (int i = 0; i < 6; ++i)
#pragma unroll
        for (int j = 0; j < 6; ++j)
            P[i*6+j] -= K[i*3+0]*T[j] + K[i*3+1]*T[6+j] + K[i*3+2]*T[12+j];

    // ---- store own row: 9x float4 @ stride 144 B ----
    {
        float4* gq = (float4*)(P_out + (size_t)t * 36);
#pragma unroll
        for (int k = 0; k < 9; ++k)
            gq[k] = make_float4(P[k*4+0], P[k*4+1], P[k*4+2], P[k*4+3]);
    }
}

extern "C" void kernel_launch(void* const* d_in, const int* in_sizes, int n_in,
                              void* d_out, int out_size, void* d_ws, size_t ws_size,
                              hipStream_t stream) {
    const float* x_in  = (const float*)d_in[0];
    const float* P_in  = (const float*)d_in[1];
    const float* dt_in = (const float*)d_in[2];
    const float* Q_in  = (const float*)d_in[3];
    const float* z_in  = (const float*)d_in[4];
    const float* R_in  = (const float*)d_in[5];

    const int B = in_sizes[2];  // delta_t is [B]

    float* x_out = (float*)d_out;                    // [B,6]
    float* P_out = (float*)d_out + (size_t)B * 6;    // [B,36]

    const int grid = (B + BLK - 1) / BLK;
    ekf_step_r7<<<grid, BLK, 0, stream>>>(x_in, P_in, dt_in, Q_in, z_in, R_in,
                                          x_out, P_out, B);
}